// Round 1
// baseline (1059.181 us; speedup 1.0000x reference)
//
#include <hip/hip_runtime.h>
#include <hip/hip_bf16.h>
#include <cstdint>
#include <cstddef>

// ---------------- constants ----------------
#define NTOK   4096          // 2*2048 tokens
#define DMODEL 1024
#define DFF    4096
#define NEXP   8
#define ROWCAP 13312         // 104 tiles * 128 rows (worst case 8192 + 8*127 pad + 4096 shared)
#define MTILES 104

typedef __attribute__((ext_vector_type(8))) short short8;
typedef __attribute__((ext_vector_type(4))) float float4v;

__device__ __forceinline__ unsigned short f2bf(float f) {
    unsigned u = __builtin_bit_cast(unsigned, f);
    u = (u + 0x7fffu + ((u >> 16) & 1u)) >> 16;
    return (unsigned short)u;
}

__device__ __forceinline__ float gelu_f(float x) {
    // jax.nn.gelu approximate=True: 0.5x(1+tanh(u)) == x*sigmoid(2u)
    float u = 0.7978845608028654f * x * (1.f + 0.044715f * x * x);
    float e = __expf(2.f * u);
    return x * (1.f - 1.f / (e + 1.f));   // safe at e->inf and e->0
}

// ---------------- h -> bf16 ----------------
__global__ __launch_bounds__(256) void cvt_h(const float* __restrict__ h,
                                             unsigned short* __restrict__ x) {
    int i = (blockIdx.x * 256 + threadIdx.x) * 4;
    float4v v = *(const float4v*)(h + i);
    ushort4 o;
    o.x = f2bf(v[0]); o.y = f2bf(v[1]); o.z = f2bf(v[2]); o.w = f2bf(v[3]);
    *(ushort4*)(x + i) = o;
}

// ---------------- router: logits -> softmax -> top2 -> compaction slots ----------------
__global__ __launch_bounds__(256) void router_k(const float* __restrict__ h,
                                                const float* __restrict__ Wr,
                                                const float* __restrict__ br,
                                                int* __restrict__ meta,
                                                int* __restrict__ slot_e,
                                                int* __restrict__ slot_pos,
                                                float* __restrict__ slot_v,
                                                float* __restrict__ out) {
    int wave = threadIdx.x >> 6, lane = threadIdx.x & 63;
    int t = blockIdx.x * 4 + wave;
    int e = lane & 7, part = lane >> 3;
    const float* hp = h + (size_t)t * DMODEL + part * 128;
    const float* wp = Wr + (size_t)part * 128 * NEXP + e;
    float acc = 0.f;
    #pragma unroll 8
    for (int j = 0; j < 128; j++) acc += hp[j] * wp[j * NEXP];
    acc += __shfl_xor(acc, 8);
    acc += __shfl_xor(acc, 16);
    acc += __shfl_xor(acc, 32);
    acc += br[e];   // lane now holds full logit for expert e = lane&7
    float lg[8];
    #pragma unroll
    for (int q = 0; q < 8; q++) lg[q] = __shfl(acc, q);
    if (lane == 0) {
        float mx = lg[0];
        #pragma unroll
        for (int q = 1; q < 8; q++) mx = fmaxf(mx, lg[q]);
        float p[8], s = 0.f;
        #pragma unroll
        for (int q = 0; q < 8; q++) { p[q] = __expf(lg[q] - mx); s += p[q]; }
        float inv = 1.f / s;
        #pragma unroll
        for (int q = 0; q < 8; q++) p[q] *= inv;
        int i1 = 0;
        #pragma unroll
        for (int q = 1; q < 8; q++) if (p[q] > p[i1]) i1 = q;   // first-occurrence ties like lax.top_k
        int i2 = (i1 == 0) ? 1 : 0;
        #pragma unroll
        for (int q = 0; q < 8; q++) if (q != i1 && p[q] > p[i2]) i2 = q;
        int pos1 = atomicAdd(&meta[i1], 1);
        int pos2 = atomicAdd(&meta[i2], 1);
        slot_e[t * 2] = i1;     slot_e[t * 2 + 1] = i2;
        slot_pos[t * 2] = pos1; slot_pos[t * 2 + 1] = pos2;
        slot_v[t * 2] = p[i1];  slot_v[t * 2 + 1] = p[i2];
        if (t == 0) out[(size_t)NTOK * DMODEL] = 0.125f;  // gate_mean == 1/E exactly
    }
}

// ---------------- meta: padded prefix sums + row-space init ----------------
__global__ __launch_bounds__(256) void meta_init(int* __restrict__ meta,
                                                 int* __restrict__ row_token,
                                                 float* __restrict__ row_weight) {
    if (threadIdx.x == 0) {
        int rb = 0;
        meta[8] = 0;
        for (int g = 0; g < 8; g++) {
            rb += ((meta[g] + 127) >> 7) << 7;   // pad each expert group to 128 rows
            meta[9 + g] = rb;
        }
        meta[17] = rb + NTOK;                    // shared group: exactly 4096 rows
    }
    for (int i = threadIdx.x; i < ROWCAP; i += 256) {
        row_token[i] = 0;
        row_weight[i] = 0.f;
    }
}

// ---------------- scatter: fill compacted row space ----------------
__global__ __launch_bounds__(256) void scatter_k(const int* __restrict__ meta,
                                                 const int* __restrict__ slot_e,
                                                 const int* __restrict__ slot_pos,
                                                 const float* __restrict__ slot_v,
                                                 int* __restrict__ row_token,
                                                 float* __restrict__ row_weight) {
    int idx = blockIdx.x * 256 + threadIdx.x;
    if (idx < NTOK * 2) {
        int e = slot_e[idx];
        int row = meta[8 + e] + slot_pos[idx];
        row_token[row] = idx >> 1;
        row_weight[row] = slot_v[idx];
    } else if (idx < NTOK * 3) {
        int t = idx - NTOK * 2;
        int row = meta[16] + t;   // shared group
        row_token[row] = t;
        row_weight[row] = 1.0f;
    }
}

// ---------------- grouped GEMM: MODE 1 = X@W1 + gelu -> Hid(bf16); MODE 2 = Hid@W2 -> atomic out
template <int MODE>
__global__ __launch_bounds__(256) void gemm_moe(
    const unsigned short* __restrict__ A,   // bf16 rows: X (mode1, gathered) or Hid (mode2)
    const float* __restrict__ Wexp,         // We1 / We2
    const float* __restrict__ Wsh,          // Ws1 / Ws2
    const float* __restrict__ bexp,         // be1 / be2
    const float* __restrict__ bsh,          // bs1 / bs2
    unsigned short* __restrict__ HidOut,    // mode1
    float* __restrict__ Out,                // mode2
    const int* __restrict__ meta,
    const int* __restrict__ row_token,
    const float* __restrict__ row_weight) {
    constexpr int K = (MODE == 1) ? DMODEL : DFF;
    constexpr int N = (MODE == 1) ? DFF : DMODEL;
    const int n0 = blockIdx.x * 128;
    const int row0 = blockIdx.y * 128;

    __shared__ int rb[10];
    if (threadIdx.x < 10) rb[threadIdx.x] = meta[8 + threadIdx.x];
    __syncthreads();
    if (row0 >= rb[9]) return;   // tail tiles beyond actual padded total
    int g = 0;
    #pragma unroll
    for (int q = 0; q < 8; q++) if (row0 >= rb[q + 1]) g = q + 1;
    const float* __restrict__ B = (g < 8) ? (Wexp + (size_t)g * K * N) : Wsh;
    const float* __restrict__ bias = (g < 8) ? (bexp + (size_t)g * N) : bsh;

    __shared__ unsigned short Asm[128 * 72];  // [m][k], stride 72 (16B-aligned frag starts)
    __shared__ unsigned short Bsm[128 * 72];  // [n][k]

    const int tid = threadIdx.x;
    const int lane = tid & 63, wave = tid >> 6;
    const int wm = wave & 1, wn = wave >> 1;
    const int lr = lane & 15, quad = lane >> 4;

    // A staging: thread -> row ar (0..127), k-half akc (32 bf16)
    const int ar = tid >> 1, akc = tid & 1;
    size_t arowbase;
    if (MODE == 1) arowbase = (size_t)row_token[row0 + ar] * K;
    else           arowbase = (size_t)(row0 + ar) * K;
    const unsigned short* aptr = A + arowbase + akc * 32;
    unsigned short* asmp = &Asm[ar * 72 + akc * 32];

    // B staging: thread -> 4 consecutive k rows (kq*4..), 8 n columns (bnc*8..)
    const int kq = tid >> 4, bnc = tid & 15;
    const float* bptr = B + (size_t)(kq * 4) * N + n0 + bnc * 8;

    float4v acc[4][4];
    #pragma unroll
    for (int i = 0; i < 4; i++)
        #pragma unroll
        for (int j = 0; j < 4; j++) acc[i][j] = (float4v){0.f, 0.f, 0.f, 0.f};

    for (int kb = 0; kb < K; kb += 64) {
        uint4 a0 = *(const uint4*)(aptr + kb);
        uint4 a1 = *(const uint4*)(aptr + kb + 8);
        uint4 a2 = *(const uint4*)(aptr + kb + 16);
        uint4 a3 = *(const uint4*)(aptr + kb + 24);
        float4v brow[4][2];
        const float* bp = bptr + (size_t)kb * N;
        #pragma unroll
        for (int r = 0; r < 4; r++) {
            brow[r][0] = *(const float4v*)(bp + (size_t)r * N);
            brow[r][1] = *(const float4v*)(bp + (size_t)r * N + 4);
        }
        __syncthreads();   // previous compute done before LDS overwrite
        *(uint4*)(asmp + 0)  = a0;
        *(uint4*)(asmp + 8)  = a1;
        *(uint4*)(asmp + 16) = a2;
        *(uint4*)(asmp + 24) = a3;
        #pragma unroll
        for (int j = 0; j < 8; j++) {        // transpose fp32->bf16 into [n][k]
            int n = bnc * 8 + j;
            ushort4 pk;
            pk.x = f2bf(brow[0][j >> 2][j & 3]);
            pk.y = f2bf(brow[1][j >> 2][j & 3]);
            pk.z = f2bf(brow[2][j >> 2][j & 3]);
            pk.w = f2bf(brow[3][j >> 2][j & 3]);
            *(ushort4*)&Bsm[n * 72 + kq * 4] = pk;   // 4 bf16 along k
        }
        __syncthreads();
        #pragma unroll
        for (int ks = 0; ks < 2; ks++) {
            short8 af[4], bf[4];
            #pragma unroll
            for (int mi = 0; mi < 4; mi++)
                af[mi] = *(const short8*)&Asm[(wm * 64 + mi * 16 + lr) * 72 + ks * 32 + quad * 8];
            #pragma unroll
            for (int ni = 0; ni < 4; ni++)
                bf[ni] = *(const short8*)&Bsm[(wn * 64 + ni * 16 + lr) * 72 + ks * 32 + quad * 8];
            #pragma unroll
            for (int mi = 0; mi < 4; mi++)
                #pragma unroll
                for (int ni = 0; ni < 4; ni++)
                    acc[mi][ni] = __builtin_amdgcn_mfma_f32_16x16x32_bf16(
                        af[mi], bf[ni], acc[mi][ni], 0, 0, 0);
        }
    }

    if (MODE == 1) {
        #pragma unroll
        for (int ni = 0; ni < 4; ni++) {
            int col = n0 + wn * 64 + ni * 16 + lr;
            float b = bias[col];
            #pragma unroll
            for (int mi = 0; mi < 4; mi++) {
                int rbase = row0 + wm * 64 + mi * 16 + quad * 4;
                #pragma unroll
                for (int r2 = 0; r2 < 4; r2++) {
                    float x = acc[mi][ni][r2] + b;
                    HidOut[(size_t)(rbase + r2) * DFF + col] = f2bf(gelu_f(x));
                }
            }
        }
    } else {
        #pragma unroll
        for (int mi = 0; mi < 4; mi++) {
            int rbase = row0 + wm * 64 + mi * 16 + quad * 4;
            int tok[4]; float w[4];
            #pragma unroll
            for (int r2 = 0; r2 < 4; r2++) {
                tok[r2] = row_token[rbase + r2];
                w[r2] = row_weight[rbase + r2];
            }
            #pragma unroll
            for (int ni = 0; ni < 4; ni++) {
                int col = n0 + wn * 64 + ni * 16 + lr;
                float b = bias[col];
                #pragma unroll
                for (int r2 = 0; r2 < 4; r2++) {
                    if (w[r2] != 0.f)
                        atomicAdd(&Out[(size_t)tok[r2] * DMODEL + col],
                                  w[r2] * (acc[mi][ni][r2] + b));
                }
            }
        }
    }
}

// ---------------- launch ----------------
extern "C" void kernel_launch(void* const* d_in, const int* in_sizes, int n_in,
                              void* d_out, int out_size, void* d_ws, size_t ws_size,
                              hipStream_t stream) {
    const float* h   = (const float*)d_in[0];
    const float* Wr  = (const float*)d_in[1];
    const float* br  = (const float*)d_in[2];
    const float* We1 = (const float*)d_in[3];
    const float* be1 = (const float*)d_in[4];
    const float* We2 = (const float*)d_in[5];
    const float* be2 = (const float*)d_in[6];
    const float* Ws1 = (const float*)d_in[7];
    const float* bs1 = (const float*)d_in[8];
    const float* Ws2 = (const float*)d_in[9];
    const float* bs2 = (const float*)d_in[10];
    float* out = (float*)d_out;

    char* ws = (char*)d_ws;
    int* meta         = (int*)ws;                      // [0..7] cnt, [8..17] rowbase
    int* slot_e       = (int*)(ws + 256);              // 8192 ints
    int* slot_pos     = (int*)(ws + 256 + 32768);      // 8192 ints
    float* slot_v     = (float*)(ws + 256 + 65536);    // 8192 floats
    int* row_token    = (int*)(ws + 98560);            // ROWCAP ints
    float* row_weight = (float*)(ws + 98560 + 53248);  // ROWCAP floats
    unsigned short* Xbf = (unsigned short*)(ws + (1ull << 20));    // 8 MB
    unsigned short* Hid = (unsigned short*)(ws + (16ull << 20));   // ~104 MB

    hipMemsetAsync(meta, 0, 256, stream);
    hipMemsetAsync(d_out, 0, sizeof(float) * (size_t)out_size, stream);
    cvt_h<<<(NTOK * DMODEL) / (256 * 4), 256, 0, stream>>>(h, Xbf);
    router_k<<<NTOK / 4, 256, 0, stream>>>(h, Wr, br, meta, slot_e, slot_pos, slot_v, out);
    meta_init<<<1, 256, 0, stream>>>(meta, row_token, row_weight);
    scatter_k<<<(NTOK * 3) / 256, 256, 0, stream>>>(meta, slot_e, slot_pos, slot_v,
                                                    row_token, row_weight);
    gemm_moe<1><<<dim3(DFF / 128, MTILES), 256, 0, stream>>>(
        Xbf, We1, Ws1, be1, bs1, Hid, nullptr, meta, row_token, row_weight);
    gemm_moe<2><<<dim3(DMODEL / 128, MTILES), 256, 0, stream>>>(
        Hid, We2, Ws2, be2, bs2, nullptr, out, meta, row_token, row_weight);
}

// Round 2
// 771.545 us; speedup vs baseline: 1.3728x; 1.3728x over previous
//
#include <hip/hip_runtime.h>
#include <hip/hip_bf16.h>
#include <cstdint>
#include <cstddef>

#define NTOK   4096
#define DMODEL 1024
#define DFF    4096
#define NEXP   8
#define ROWCAP 13312         // 52*256; 104 tiles * 128 rows worst case
#define MTILES 104

typedef __attribute__((ext_vector_type(8))) short short8;
typedef __attribute__((ext_vector_type(4))) float float4v;

__device__ __forceinline__ unsigned short f2bf(float f) {
    unsigned u = __builtin_bit_cast(unsigned, f);
    u = (u + 0x7fffu + ((u >> 16) & 1u)) >> 16;
    return (unsigned short)u;
}

__device__ __forceinline__ float gelu_f(float x) {
    float u = 0.7978845608028654f * x * (1.f + 0.044715f * x * x);
    float e = __expf(2.f * u);
    return x * (1.f - 1.f / (e + 1.f));
}

__device__ __forceinline__ void gl_lds16(const unsigned short* g, unsigned short* l) {
    __builtin_amdgcn_global_load_lds((const __attribute__((address_space(1))) void*)g,
                                     (__attribute__((address_space(3))) void*)l, 16, 0, 0);
}

// ---------------- router + h->bf16 fused ----------------
// block = 256 threads = 16 tokens; thread (tok=tid>>4, part=tid&15) covers 64 elems
__global__ __launch_bounds__(256) void router_k(const float* __restrict__ h,
                                                const float* __restrict__ Wr,
                                                const float* __restrict__ br,
                                                int* __restrict__ meta,
                                                int* __restrict__ slot_e,
                                                int* __restrict__ slot_pos,
                                                float* __restrict__ slot_v,
                                                unsigned short* __restrict__ Xbf,
                                                float* __restrict__ out) {
    __shared__ float wr_s[16 * 516];   // 16 chunks of 64 rows x 8 experts, +4 pad/chunk
    const int tid = threadIdx.x;
    for (int i = tid; i < 8192; i += 256) {
        int j = i >> 3, e = i & 7;
        wr_s[(j >> 6) * 516 + (j & 63) * 8 + e] = Wr[i];
    }
    __syncthreads();
    const int tok = blockIdx.x * 16 + (tid >> 4);
    const int part = tid & 15;
    const float* hp = h + (size_t)tok * DMODEL + part * 64;
    unsigned short* xp = Xbf + (size_t)tok * DMODEL + part * 64;
    const float* wbase = &wr_s[part * 516];
    float acc8[8] = {0.f, 0.f, 0.f, 0.f, 0.f, 0.f, 0.f, 0.f};
    #pragma unroll
    for (int j4 = 0; j4 < 16; j4++) {
        float4v hv = *(const float4v*)(hp + j4 * 4);
        ushort4 o;
        o.x = f2bf(hv[0]); o.y = f2bf(hv[1]); o.z = f2bf(hv[2]); o.w = f2bf(hv[3]);
        *(ushort4*)(xp + j4 * 4) = o;
        #pragma unroll
        for (int jj = 0; jj < 4; jj++) {
            const float* wr = wbase + (j4 * 4 + jj) * 8;
            float4v w0 = *(const float4v*)wr;
            float4v w1 = *(const float4v*)(wr + 4);
            #pragma unroll
            for (int e = 0; e < 4; e++) {
                acc8[e]     = fmaf(hv[jj], w0[e], acc8[e]);
                acc8[e + 4] = fmaf(hv[jj], w1[e], acc8[e + 4]);
            }
        }
    }
    #pragma unroll
    for (int e = 0; e < 8; e++) {
        acc8[e] += __shfl_xor(acc8[e], 1);
        acc8[e] += __shfl_xor(acc8[e], 2);
        acc8[e] += __shfl_xor(acc8[e], 4);
        acc8[e] += __shfl_xor(acc8[e], 8);
    }
    if (part == 0) {
        float p[8];
        float mx = -1e30f;
        #pragma unroll
        for (int e = 0; e < 8; e++) { p[e] = acc8[e] + br[e]; mx = fmaxf(mx, p[e]); }
        float s = 0.f;
        #pragma unroll
        for (int e = 0; e < 8; e++) { p[e] = __expf(p[e] - mx); s += p[e]; }
        float inv = 1.f / s;
        #pragma unroll
        for (int e = 0; e < 8; e++) p[e] *= inv;
        int i1 = 0;
        #pragma unroll
        for (int q = 1; q < 8; q++) if (p[q] > p[i1]) i1 = q;
        int i2 = (i1 == 0) ? 1 : 0;
        #pragma unroll
        for (int q = 0; q < 8; q++) if (q != i1 && p[q] > p[i2]) i2 = q;
        int pos1 = atomicAdd(&meta[i1], 1);
        int pos2 = atomicAdd(&meta[i2], 1);
        slot_e[tok * 2] = i1;     slot_e[tok * 2 + 1] = i2;
        slot_pos[tok * 2] = pos1; slot_pos[tok * 2 + 1] = pos2;
        slot_v[tok * 2] = p[i1];  slot_v[tok * 2 + 1] = p[i2];
    }
    if (blockIdx.x == 0 && tid == 0) out[(size_t)NTOK * DMODEL] = 0.125f;
}

// ---------------- meta: prefix + row init (grid 52) ----------------
__global__ __launch_bounds__(256) void meta_init(int* __restrict__ meta,
                                                 int* __restrict__ row_token,
                                                 float* __restrict__ row_weight) {
    int i = blockIdx.x * 256 + threadIdx.x;
    if (i < ROWCAP) { row_token[i] = 0; row_weight[i] = 0.f; }
    if (blockIdx.x == 0 && threadIdx.x == 0) {
        int rb = 0;
        meta[8] = 0;
        for (int g = 0; g < 8; g++) {
            rb += ((meta[g] + 127) >> 7) << 7;
            meta[9 + g] = rb;
        }
        meta[17] = rb + NTOK;
    }
}

// ---------------- scatter ----------------
__global__ __launch_bounds__(256) void scatter_k(const int* __restrict__ meta,
                                                 const int* __restrict__ slot_e,
                                                 const int* __restrict__ slot_pos,
                                                 const float* __restrict__ slot_v,
                                                 int* __restrict__ row_token,
                                                 float* __restrict__ row_weight) {
    int idx = blockIdx.x * 256 + threadIdx.x;
    if (idx < NTOK * 2) {
        int e = slot_e[idx];
        int row = meta[8 + e] + slot_pos[idx];
        row_token[row] = idx >> 1;
        row_weight[row] = slot_v[idx];
    } else if (idx < NTOK * 3) {
        int t = idx - NTOK * 2;
        row_token[meta[16] + t] = t;
        row_weight[meta[16] + t] = 1.0f;
    }
}

// ---------------- weight transpose+convert: src [K][N] fp32 -> dst [N][K] bf16 ----------------
__global__ __launch_bounds__(256) void wtrans(const float* __restrict__ Wexp,
                                              const float* __restrict__ Wsh,
                                              unsigned short* __restrict__ dst,
                                              int K, int N) {
    const int g = blockIdx.z;
    const float* src = (g < 8) ? (Wexp + (size_t)g * K * N) : Wsh;
    unsigned short* d = dst + (size_t)g * K * N;
    const int n0 = blockIdx.x * 64, k0 = blockIdx.y * 64;
    __shared__ float t[64 * 65];
    const int r = threadIdx.x >> 4, c4 = (threadIdx.x & 15) * 4;
    #pragma unroll
    for (int i = 0; i < 4; i++) {
        float4v v = *(const float4v*)(src + (size_t)(k0 + r + i * 16) * N + n0 + c4);
        float* tp = &t[(r + i * 16) * 65 + c4];
        tp[0] = v[0]; tp[1] = v[1]; tp[2] = v[2]; tp[3] = v[3];
    }
    __syncthreads();
    #pragma unroll
    for (int i = 0; i < 4; i++) {
        int n = r + i * 16;
        ushort4 o;
        o.x = f2bf(t[(c4 + 0) * 65 + n]);
        o.y = f2bf(t[(c4 + 1) * 65 + n]);
        o.z = f2bf(t[(c4 + 2) * 65 + n]);
        o.w = f2bf(t[(c4 + 3) * 65 + n]);
        *(ushort4*)(d + (size_t)(n0 + n) * K + k0 + c4) = o;
    }
}

// ---------------- grouped GEMM, m97-style K-loop ----------------
// MODE 1: X(gathered) @ W1T -> gelu -> Hid(bf16). MODE 2: Hid @ W2T -> atomic out.
template <int MODE>
__global__ __launch_bounds__(256) void gemm_moe(
    const unsigned short* __restrict__ A,
    const unsigned short* __restrict__ WT,    // [9][N][K] bf16
    const float* __restrict__ bexp,
    const float* __restrict__ bsh,
    unsigned short* __restrict__ HidOut,
    float* __restrict__ Out,
    const int* __restrict__ meta,
    const int* __restrict__ row_token,
    const float* __restrict__ row_weight) {
    constexpr int K = (MODE == 1) ? DMODEL : DFF;
    constexpr int N = (MODE == 1) ? DFF : DMODEL;
    const int row0 = blockIdx.x * 128;
    const int n0 = blockIdx.y * 128;

    __shared__ int rb[10];
    __shared__ unsigned short sm[17408];   // 2x 128x64 staging; epilogue C-tile 128x136

    if (threadIdx.x < 10) rb[threadIdx.x] = meta[8 + threadIdx.x];
    __syncthreads();
    if (row0 >= rb[9]) return;
    int g = 0;
    #pragma unroll
    for (int q = 0; q < 8; q++) if (row0 >= rb[q + 1]) g = q + 1;
    const unsigned short* __restrict__ BT = WT + (size_t)g * K * N;
    const float* __restrict__ bias = (g < 8) ? (bexp + (size_t)g * N) : bsh;

    const int tid = threadIdx.x;
    const int wave = tid >> 6, lane = tid & 63;
    const int lrow8 = lane >> 3, kst = lane & 7;
    const int swz = kst ^ lrow8;           // global k-part this lane fetches
    const int wm = wave & 1, wn = wave >> 1;
    const int lr = lane & 15, quad = lane >> 4, l7 = lr & 7;

    const unsigned short* ag[4];
    const unsigned short* bg[4];
    unsigned short* al[4];
    unsigned short* bl[4];
    #pragma unroll
    for (int s = 0; s < 4; s++) {
        int seg = wave * 4 + s;
        int row = seg * 8 + lrow8;
        size_t arow = (MODE == 1) ? (size_t)row_token[row0 + row] : (size_t)(row0 + row);
        ag[s] = A + arow * K + swz * 8;
        bg[s] = BT + (size_t)(n0 + row) * K + swz * 8;
        al[s] = &sm[seg * 512];
        bl[s] = &sm[8192 + seg * 512];
    }

    float4v acc[4][4];
    #pragma unroll
    for (int i = 0; i < 4; i++)
        #pragma unroll
        for (int j = 0; j < 4; j++) acc[i][j] = (float4v){0.f, 0.f, 0.f, 0.f};

    for (int kb = 0; kb < K; kb += 64) {
        #pragma unroll
        for (int s = 0; s < 4; s++) gl_lds16(ag[s] + kb, al[s]);
        #pragma unroll
        for (int s = 0; s < 4; s++) gl_lds16(bg[s] + kb, bl[s]);
        __syncthreads();   // vmcnt(0) drain: staging visible to all
        #pragma unroll
        for (int ks = 0; ks < 2; ks++) {
            const int koff = ((ks * 4 + quad) ^ l7) * 8;
            short8 af[4], bf[4];
            #pragma unroll
            for (int mi = 0; mi < 4; mi++)
                af[mi] = *(const short8*)&sm[(wm * 64 + mi * 16 + lr) * 64 + koff];
            #pragma unroll
            for (int ni = 0; ni < 4; ni++)
                bf[ni] = *(const short8*)&sm[8192 + (wn * 64 + ni * 16 + lr) * 64 + koff];
            #pragma unroll
            for (int mi = 0; mi < 4; mi++)
                #pragma unroll
                for (int ni = 0; ni < 4; ni++)
                    acc[mi][ni] = __builtin_amdgcn_mfma_f32_16x16x32_bf16(
                        af[mi], bf[ni], acc[mi][ni], 0, 0, 0);
        }
        __syncthreads();   // protect staging from next iter overwrite
    }

    if (MODE == 1) {
        // gelu -> bf16 into LDS [128][136], then fully-coalesced 16B stores
        #pragma unroll
        for (int ni = 0; ni < 4; ni++) {
            int col = wn * 64 + ni * 16 + lr;
            float b = bias[n0 + col];
            #pragma unroll
            for (int mi = 0; mi < 4; mi++) {
                int rowb = wm * 64 + mi * 16 + quad * 4;
                #pragma unroll
                for (int r2 = 0; r2 < 4; r2++)
                    sm[(rowb + r2) * 136 + col] = f2bf(gelu_f(acc[mi][ni][r2] + b));
            }
        }
        __syncthreads();
        const int row = tid >> 1, half = tid & 1;
        const unsigned short* srcp = &sm[row * 136 + half * 64];
        unsigned short* dstp = &HidOut[(size_t)(row0 + row) * DFF + n0 + half * 64];
        #pragma unroll
        for (int j = 0; j < 8; j++)
            *(uint4*)(dstp + j * 8) = *(const uint4*)(srcp + j * 8);
    } else {
        #pragma unroll
        for (int mi = 0; mi < 4; mi++) {
            int rbase = row0 + wm * 64 + mi * 16 + quad * 4;
            int tok[4]; float w[4];
            #pragma unroll
            for (int r2 = 0; r2 < 4; r2++) {
                tok[r2] = row_token[rbase + r2];
                w[r2] = row_weight[rbase + r2];
            }
            #pragma unroll
            for (int ni = 0; ni < 4; ni++) {
                int col = n0 + wn * 64 + ni * 16 + lr;
                float b = bias[col];
                #pragma unroll
                for (int r2 = 0; r2 < 4; r2++) {
                    if (w[r2] != 0.f)
                        atomicAdd(&Out[(size_t)tok[r2] * DMODEL + col],
                                  w[r2] * (acc[mi][ni][r2] + b));
                }
            }
        }
    }
}

// ---------------- launch ----------------
extern "C" void kernel_launch(void* const* d_in, const int* in_sizes, int n_in,
                              void* d_out, int out_size, void* d_ws, size_t ws_size,
                              hipStream_t stream) {
    const float* h   = (const float*)d_in[0];
    const float* Wr  = (const float*)d_in[1];
    const float* br  = (const float*)d_in[2];
    const float* We1 = (const float*)d_in[3];
    const float* be1 = (const float*)d_in[4];
    const float* We2 = (const float*)d_in[5];
    const float* be2 = (const float*)d_in[6];
    const float* Ws1 = (const float*)d_in[7];
    const float* bs1 = (const float*)d_in[8];
    const float* Ws2 = (const float*)d_in[9];
    const float* bs2 = (const float*)d_in[10];
    float* out = (float*)d_out;

    char* ws = (char*)d_ws;
    int* meta         = (int*)ws;
    int* slot_e       = (int*)(ws + 4096);
    int* slot_pos     = (int*)(ws + 36864);
    float* slot_v     = (float*)(ws + 69632);
    int* row_token    = (int*)(ws + 102400);
    float* row_weight = (float*)(ws + 155648);
    unsigned short* Xbf = (unsigned short*)(ws + (1ull << 20));   // 8 MB
    unsigned short* WT  = (unsigned short*)(ws + (16ull << 20));  // 75.5 MB (W1T then W2T)
    unsigned short* Hid = (unsigned short*)(ws + (96ull << 20));  // 104 MB

    hipMemsetAsync(meta, 0, 256, stream);
    hipMemsetAsync(d_out, 0, sizeof(float) * (size_t)out_size, stream);
    router_k<<<NTOK / 16, 256, 0, stream>>>(h, Wr, br, meta, slot_e, slot_pos, slot_v, Xbf, out);
    meta_init<<<ROWCAP / 256, 256, 0, stream>>>(meta, row_token, row_weight);
    scatter_k<<<(NTOK * 3) / 256, 256, 0, stream>>>(meta, slot_e, slot_pos, slot_v,
                                                    row_token, row_weight);
    // W1^T : [9][4096][1024] bf16
    wtrans<<<dim3(DFF / 64, DMODEL / 64, 9), 256, 0, stream>>>(We1, Ws1, WT, DMODEL, DFF);
    gemm_moe<1><<<dim3(MTILES, DFF / 128), 256, 0, stream>>>(
        Xbf, WT, be1, bs1, Hid, nullptr, meta, row_token, row_weight);
    // W2^T : [9][1024][4096] bf16 (overwrites W1T region; gemm1 already done in-stream)
    wtrans<<<dim3(DMODEL / 64, DFF / 64, 9), 256, 0, stream>>>(We2, Ws2, WT, DFF, DMODEL);
    gemm_moe<2><<<dim3(MTILES, DMODEL / 128), 256, 0, stream>>>(
        Hid, WT, be2, bs2, nullptr, out, meta, row_token, row_weight);
}